// Round 3
// baseline (417.373 us; speedup 1.0000x reference)
//
#include <hip/hip_runtime.h>
#include <hip/hip_bf16.h>
#include <stdint.h>

#define B_ROWS 8192
#define DIM 256
#define JCHUNK 256
#define WPB 4  // waves per block
#define ROWS_PER_WAVE 32
#define ROWS_PER_BLOCK (WPB * ROWS_PER_WAVE)  // 128
#define NT (JCHUNK / 16)                      // 16 j-tiles per block

typedef __bf16 bf16x8 __attribute__((ext_vector_type(8)));
typedef float f32x4 __attribute__((ext_vector_type(4)));

#if __has_builtin(__builtin_amdgcn_exp2f)
#define EXP2F(x) __builtin_amdgcn_exp2f(x)
#else
#define EXP2F(x) exp2f(x)
#endif

__device__ __forceinline__ unsigned short f2bf_rne(float f) {
    unsigned int u = __builtin_bit_cast(unsigned int, f);
    unsigned int r = (u + 0x7FFFu + ((u >> 16) & 1u)) >> 16;
    return (unsigned short)r;
}

// swizzled LDS tile: 16 rows x 512B; chunk c (16B) of row r at r*512 + ((c^r)&31)*16
__device__ __forceinline__ void stw(unsigned char* buf, int r, int c, uint4 v) {
    *reinterpret_cast<uint4*>(&buf[r * 512 + ((c ^ r) & 31) * 16]) = v;
}

// ---------------- Kernel 1: L2-normalize rows -> bf16, plus zero accumulators ----------------
__global__ __launch_bounds__(256) void normalize_k(const float* __restrict__ emb,
                                                   unsigned short* __restrict__ ebf,
                                                   float* __restrict__ Sall,  // 2*8192 floats contiguous
                                                   int* __restrict__ done_ctr) {
    const int idx = blockIdx.x * 256 + threadIdx.x;
    // zero Sall+Spos (16384 floats = 4096 float4) and the done counter
    if (idx < 4096) {
        float4 z = {0.f, 0.f, 0.f, 0.f};
        reinterpret_cast<float4*>(Sall)[idx] = z;
    }
    if (idx == 4096) *done_ctr = 0;

    const int row = blockIdx.x * 4 + (threadIdx.x >> 6);
    const int lane = threadIdx.x & 63;  // 4 floats each covers DIM=256
    const float4 v = reinterpret_cast<const float4*>(emb + (size_t)row * DIM)[lane];
    float ss = v.x * v.x + v.y * v.y + v.z * v.z + v.w * v.w;
    #pragma unroll
    for (int off = 32; off; off >>= 1) ss += __shfl_xor(ss, off);
    const float scale = 1.0f / fmaxf(sqrtf(ss), 1e-12f);
    ushort4 o;
    o.x = f2bf_rne(v.x * scale);
    o.y = f2bf_rne(v.y * scale);
    o.z = f2bf_rne(v.z * scale);
    o.w = f2bf_rne(v.w * scale);
    reinterpret_cast<ushort4*>(ebf + (size_t)row * DIM)[lane] = o;
}

// ---------------- Kernel 2: fused sim + masked exp-sum + (last block) finalize ----------------
// A (32 rows/wave, K=256) register(AGPR)-resident. B-tile 16 cols x 512B staged in LDS,
// TRIPLE-buffered with register-held depth-2 prefetch: loads for tile jt+2 issue at iter jt,
// are written to LDS at iter jt+1 -> a full iteration of slack before the vmcnt drain.
__global__ __launch_bounds__(256, 3) void sim_k(const unsigned short* __restrict__ ebf,
                                                const int* __restrict__ labels,
                                                float* __restrict__ Sall,
                                                float* __restrict__ Spos,
                                                int* __restrict__ done_ctr,
                                                float* __restrict__ out) {
    // exp((dot-1)/T) = exp2((dot-1) * INV_T*log2e)
    constexpr float K2 = 14.285714285714286f * 1.4426950408889634f;  // 20.60993
    __shared__ __align__(16) unsigned char lds[3][8192];
    __shared__ int is_last;
    __shared__ float ssum[WPB];
    __shared__ int scnt[WPB];

    const int tid  = threadIdx.x;
    const int wave = tid >> 6;
    const int lane = tid & 63;
    const int col  = lane & 15;
    const int quad = lane >> 4;

    const int jblocks = B_ROWS / JCHUNK;           // 32
    const int rowblk  = blockIdx.x / jblocks;      // 0..63
    const int jblk    = blockIdx.x % jblocks;
    const int i_base  = rowblk * ROWS_PER_BLOCK + wave * ROWS_PER_WAVE;
    const int j0      = jblk * JCHUNK;

    // ---- Preload A-fragments (2 tiles x 8 K-steps) + row labels ----
    bf16x8 afrag[2][8];
    int li[2][4];
    #pragma unroll
    for (int t = 0; t < 2; ++t) {
        const int arow = i_base + t * 16 + col;
        const uint4* ap = reinterpret_cast<const uint4*>(ebf) + (size_t)arow * 32 + quad;
        #pragma unroll
        for (int kk = 0; kk < 8; ++kk)
            afrag[t][kk] = __builtin_bit_cast(bf16x8, ap[kk * 4]);
        #pragma unroll
        for (int r = 0; r < 4; ++r)
            li[t][r] = labels[i_base + t * 16 + quad * 4 + r];
    }

    const int st_r = tid >> 5;      // 0..7
    const int st_c = tid & 31;
    const uint4* gB = reinterpret_cast<const uint4*>(ebf);

    // ---- Prologue: tile0 -> p[0] -> lds[0]; tile1 -> p[1] (held in regs) ----
    uint4 p[2][2];
    p[0][0] = gB[(size_t)(j0 + st_r) * 32 + st_c];
    p[0][1] = gB[(size_t)(j0 + 8 + st_r) * 32 + st_c];
    p[1][0] = gB[(size_t)(j0 + 16 + st_r) * 32 + st_c];
    p[1][1] = gB[(size_t)(j0 + 24 + st_r) * 32 + st_c];
    stw(lds[0], st_r, st_c, p[0][0]);
    stw(lds[0], st_r + 8, st_c, p[0][1]);
    __syncthreads();

    float s_all[2][4] = {};
    float s_pos[2][4] = {};

    for (int jt = 0; jt < NT; ++jt) {
        // B-fragments from LDS (swizzled)
        bf16x8 bfrag[8];
        #pragma unroll
        for (int kk = 0; kk < 8; ++kk) {
            const int c = kk * 4 + quad;
            bfrag[kk] = *reinterpret_cast<const bf16x8*>(
                &lds[jt % 3][col * 512 + ((c ^ col) & 31) * 16]);
        }
        const int jcol = j0 + jt * 16 + col;
        const int lj = labels[jcol];

        // issue loads for tile jt+2 into p[jt&1] (that slot's data was written to LDS last iter)
        if (jt + 2 < NT) {
            const int jn = j0 + (jt + 2) * 16;
            p[jt & 1][0] = gB[(size_t)(jn + st_r) * 32 + st_c];
            p[jt & 1][1] = gB[(size_t)(jn + 8 + st_r) * 32 + st_c];
        }

        f32x4 acc0 = {0.f, 0.f, 0.f, 0.f};
        f32x4 acc1 = {0.f, 0.f, 0.f, 0.f};
        #pragma unroll
        for (int kk = 0; kk < 8; ++kk) {
            acc0 = __builtin_amdgcn_mfma_f32_16x16x32_bf16(afrag[0][kk], bfrag[kk], acc0, 0, 0, 0);
            acc1 = __builtin_amdgcn_mfma_f32_16x16x32_bf16(afrag[1][kk], bfrag[kk], acc1, 0, 0, 0);
        }

        // Epilogue. D[row = quad*4+r][col]. Diagonal only possible when this 16-col
        // strip overlaps the wave's 32-row strip (wave-uniform branch).
        const int jt16 = j0 + jt * 16;
        const bool diag_possible = (jt16 < i_base + 32) && (i_base < jt16 + 16);
        if (!diag_possible) {
            #pragma unroll
            for (int t = 0; t < 2; ++t) {
                const f32x4 acc = t ? acc1 : acc0;
                #pragma unroll
                for (int r = 0; r < 4; ++r) {
                    const float ex = EXP2F(fmaf(acc[r], K2, -K2));
                    s_all[t][r] += ex;
                    s_pos[t][r] += (lj == li[t][r]) ? ex : 0.0f;
                }
            }
        } else {
            #pragma unroll
            for (int t = 0; t < 2; ++t) {
                const f32x4 acc = t ? acc1 : acc0;
                #pragma unroll
                for (int r = 0; r < 4; ++r) {
                    const int irow = i_base + t * 16 + quad * 4 + r;
                    const float ex = EXP2F(fmaf(acc[r], K2, -K2));
                    const bool valid = (jcol != irow);
                    const bool pos = valid && (lj == li[t][r]);
                    s_all[t][r] += valid ? ex : 0.0f;
                    s_pos[t][r] += pos ? ex : 0.0f;
                }
            }
        }

        // write tile jt+1 (held in p[(jt+1)&1] since last iter) into lds[(jt+1)%3]
        if (jt + 1 < NT) {
            unsigned char* dst = lds[(jt + 1) % 3];
            const int s = (jt + 1) & 1;
            stw(dst, st_r, st_c, p[s][0]);
            stw(dst, st_r + 8, st_c, p[s][1]);
        }
        __syncthreads();
    }

    // Reduce over the 16 column-lanes within each quad, then one atomic per row.
    #pragma unroll
    for (int t = 0; t < 2; ++t) {
        #pragma unroll
        for (int r = 0; r < 4; ++r) {
            float a = s_all[t][r];
            float pp = s_pos[t][r];
            #pragma unroll
            for (int off = 1; off < 16; off <<= 1) {
                a += __shfl_xor(a, off);
                pp += __shfl_xor(pp, off);
            }
            if (col == 0) {
                const int irow = i_base + t * 16 + quad * 4 + r;
                atomicAdd(&Sall[irow], a);
                atomicAdd(&Spos[irow], pp);
            }
        }
    }

    // ---- Last block finalizes ----
    __threadfence();
    if (tid == 0) {
        const int old = __hip_atomic_fetch_add(done_ctr, 1, __ATOMIC_ACQ_REL,
                                               __HIP_MEMORY_SCOPE_AGENT);
        is_last = (old == (int)(gridDim.x - 1));
    }
    __syncthreads();
    if (!is_last) return;

    float sum = 0.0f;
    int cnt = 0;
    for (int i = tid; i < B_ROWS; i += 256) {
        const float sp = __hip_atomic_load(&Spos[i], __ATOMIC_RELAXED, __HIP_MEMORY_SCOPE_AGENT);
        const float sa = __hip_atomic_load(&Sall[i], __ATOMIC_RELAXED, __HIP_MEMORY_SCOPE_AGENT);
        if (sp > 0.0f) {
            sum += __logf(sa) - __logf(sp);  // fixed max M cancels
            ++cnt;
        }
    }
    #pragma unroll
    for (int off = 32; off; off >>= 1) {
        sum += __shfl_xor(sum, off);
        cnt += __shfl_xor(cnt, off);
    }
    if (lane == 0) { ssum[wave] = sum; scnt[wave] = cnt; }
    __syncthreads();
    if (tid == 0) {
        float s = 0.0f;
        int c = 0;
        #pragma unroll
        for (int w = 0; w < WPB; ++w) { s += ssum[w]; c += scnt[w]; }
        out[0] = (c > 0) ? s / (float)c : 0.0f;
    }
}

extern "C" void kernel_launch(void* const* d_in, const int* in_sizes, int n_in,
                              void* d_out, int out_size, void* d_ws, size_t ws_size,
                              hipStream_t stream) {
    const float* emb   = (const float*)d_in[0];
    const int* labels  = (const int*)d_in[1];
    float* out         = (float*)d_out;

    unsigned short* ebf = (unsigned short*)d_ws;                       // 4 MB bf16 normalized
    float* Sall = (float*)((char*)d_ws + (size_t)B_ROWS * DIM * 2);    // 32 KB
    float* Spos = Sall + B_ROWS;                                       // 32 KB
    int* done_ctr = (int*)(Spos + B_ROWS);

    normalize_k<<<B_ROWS / 4, 256, 0, stream>>>(emb, ebf, Sall, done_ctr);

    dim3 grid((B_ROWS / ROWS_PER_BLOCK) * (B_ROWS / JCHUNK));          // 64*32 = 2048
    sim_k<<<grid, 256, 0, stream>>>(ebf, labels, Sall, Spos, done_ctr, out);
}

// Round 4
// 360.591 us; speedup vs baseline: 1.1575x; 1.1575x over previous
//
#include <hip/hip_runtime.h>
#include <hip/hip_bf16.h>
#include <stdint.h>

#define B_ROWS 8192
#define DIM 256
#define JCHUNK 256
#define WPB 4  // waves per block
#define ROWS_PER_WAVE 32
#define ROWS_PER_BLOCK (WPB * ROWS_PER_WAVE)  // 128
#define NT (JCHUNK / 16)                      // 16 j-tiles per block (even, required by x2 unroll)

typedef __bf16 bf16x8 __attribute__((ext_vector_type(8)));
typedef float f32x4 __attribute__((ext_vector_type(4)));

#if __has_builtin(__builtin_amdgcn_exp2f)
#define EXP2F(x) __builtin_amdgcn_exp2f(x)
#else
#define EXP2F(x) exp2f(x)
#endif

__device__ __forceinline__ unsigned short f2bf_rne(float f) {
    unsigned int u = __builtin_bit_cast(unsigned int, f);
    unsigned int r = (u + 0x7FFFu + ((u >> 16) & 1u)) >> 16;
    return (unsigned short)r;
}

// swizzled LDS tile: 16 rows x 512B; chunk c (16B) of row r at r*512 + ((c^r)&31)*16
__device__ __forceinline__ void stw(unsigned char* buf, int r, int c, uint4 v) {
    *reinterpret_cast<uint4*>(&buf[r * 512 + ((c ^ r) & 31) * 16]) = v;
}

// ---------------- Kernel 1: L2-normalize rows -> bf16, plus zero accumulators ----------------
__global__ __launch_bounds__(256) void normalize_k(const float* __restrict__ emb,
                                                   unsigned short* __restrict__ ebf,
                                                   float* __restrict__ Sall,  // 2*8192 floats contiguous
                                                   int* __restrict__ done_ctr) {
    const int idx = blockIdx.x * 256 + threadIdx.x;
    if (idx < 4096) {
        float4 z = {0.f, 0.f, 0.f, 0.f};
        reinterpret_cast<float4*>(Sall)[idx] = z;
    }
    if (idx == 4096) *done_ctr = 0;

    const int row = blockIdx.x * 4 + (threadIdx.x >> 6);
    const int lane = threadIdx.x & 63;  // 4 floats each covers DIM=256
    const float4 v = reinterpret_cast<const float4*>(emb + (size_t)row * DIM)[lane];
    float ss = v.x * v.x + v.y * v.y + v.z * v.z + v.w * v.w;
    #pragma unroll
    for (int off = 32; off; off >>= 1) ss += __shfl_xor(ss, off);
    const float scale = 1.0f / fmaxf(sqrtf(ss), 1e-12f);
    ushort4 o;
    o.x = f2bf_rne(v.x * scale);
    o.y = f2bf_rne(v.y * scale);
    o.z = f2bf_rne(v.z * scale);
    o.w = f2bf_rne(v.w * scale);
    reinterpret_cast<ushort4*>(ebf + (size_t)row * DIM)[lane] = o;
}

// ---------------- Kernel 2: fused sim + masked exp-sum + (last block) finalize ----------------
// A (32 rows/wave, K=256) register(AGPR)-resident. B-tile 16 cols x 512B in LDS,
// double-buffered with depth-2 register prefetch, manually unrolled x2 so every
// register name and LDS buffer index is a compile-time constant (NO scratch).
__global__ __launch_bounds__(256, 3) void sim_k(const unsigned short* __restrict__ ebf,
                                                const int* __restrict__ labels,
                                                float* __restrict__ Sall,
                                                float* __restrict__ Spos,
                                                int* __restrict__ done_ctr,
                                                float* __restrict__ out) {
    // exp((dot-1)/T) = exp2((dot-1) * INV_T*log2e)
    constexpr float K2 = 14.285714285714286f * 1.4426950408889634f;  // 20.60993
    __shared__ __align__(16) unsigned char lds0[8192];
    __shared__ __align__(16) unsigned char lds1[8192];
    __shared__ int lds_lab[JCHUNK];
    __shared__ int is_last;
    __shared__ float ssum[WPB];
    __shared__ int scnt[WPB];

    const int tid  = threadIdx.x;
    const int wave = tid >> 6;
    const int lane = tid & 63;
    const int col  = lane & 15;
    const int quad = lane >> 4;

    const int jblocks = B_ROWS / JCHUNK;           // 32
    const int rowblk  = blockIdx.x / jblocks;      // 0..63
    const int jblk    = blockIdx.x % jblocks;
    const int i_base  = rowblk * ROWS_PER_BLOCK + wave * ROWS_PER_WAVE;
    const int j0      = jblk * JCHUNK;

    // ---- Preload A-fragments (2 tiles x 8 K-steps) + row labels ----
    bf16x8 afrag[2][8];
    int li[2][4];
    #pragma unroll
    for (int t = 0; t < 2; ++t) {
        const int arow = i_base + t * 16 + col;
        const uint4* ap = reinterpret_cast<const uint4*>(ebf) + (size_t)arow * 32 + quad;
        #pragma unroll
        for (int kk = 0; kk < 8; ++kk)
            afrag[t][kk] = __builtin_bit_cast(bf16x8, ap[kk * 4]);
        #pragma unroll
        for (int r = 0; r < 4; ++r)
            li[t][r] = labels[i_base + t * 16 + quad * 4 + r];
    }

    const int st_r = tid >> 5;      // 0..7
    const int st_c = tid & 31;
    const uint4* gB = reinterpret_cast<const uint4*>(ebf);

    // ---- Prologue: tile0 -> pA -> lds0; tile1 -> pB (held in regs); labels -> LDS ----
    uint4 pA0 = gB[(size_t)(j0 + st_r) * 32 + st_c];
    uint4 pA1 = gB[(size_t)(j0 + 8 + st_r) * 32 + st_c];
    uint4 pB0 = gB[(size_t)(j0 + 16 + st_r) * 32 + st_c];
    uint4 pB1 = gB[(size_t)(j0 + 24 + st_r) * 32 + st_c];
    lds_lab[tid] = labels[j0 + tid];
    stw(lds0, st_r, st_c, pA0);
    stw(lds0, st_r + 8, st_c, pA1);
    __syncthreads();

    float s_all[2][4] = {};
    float s_pos[2][4] = {};

    // One pipeline stage: read frags from ldsR (tile jt), prefetch tile jt+2 into
    // (pf0,pf1), MFMA+epilogue, write tile jt+1 (wr0,wr1) into ldsW, barrier.
    #define STAGE(JT, LDSR, LDSW, PF0, PF1, WR0, WR1)                                   \
    {                                                                                   \
        const int jt = (JT);                                                            \
        bf16x8 bfrag[8];                                                                \
        _Pragma("unroll")                                                               \
        for (int kk = 0; kk < 8; ++kk) {                                                \
            const int c = kk * 4 + quad;                                                \
            bfrag[kk] = *reinterpret_cast<const bf16x8*>(                               \
                &LDSR[col * 512 + ((c ^ col) & 31) * 16]);                              \
        }                                                                               \
        const int jcol = j0 + jt * 16 + col;                                            \
        const int lj = lds_lab[jt * 16 + col];                                          \
        if (jt + 2 < NT) {                                                              \
            const int jn = j0 + (jt + 2) * 16;                                          \
            PF0 = gB[(size_t)(jn + st_r) * 32 + st_c];                                  \
            PF1 = gB[(size_t)(jn + 8 + st_r) * 32 + st_c];                              \
        }                                                                               \
        f32x4 acc0 = {0.f, 0.f, 0.f, 0.f};                                              \
        f32x4 acc1 = {0.f, 0.f, 0.f, 0.f};                                              \
        _Pragma("unroll")                                                               \
        for (int kk = 0; kk < 8; ++kk) {                                                \
            acc0 = __builtin_amdgcn_mfma_f32_16x16x32_bf16(afrag[0][kk], bfrag[kk],     \
                                                           acc0, 0, 0, 0);              \
            acc1 = __builtin_amdgcn_mfma_f32_16x16x32_bf16(afrag[1][kk], bfrag[kk],     \
                                                           acc1, 0, 0, 0);              \
        }                                                                               \
        const int jt16 = j0 + jt * 16;                                                  \
        const bool diag_possible = (jt16 < i_base + 32) && (i_base < jt16 + 16);        \
        if (!diag_possible) {                                                           \
            _Pragma("unroll")                                                           \
            for (int t = 0; t < 2; ++t) {                                               \
                const f32x4 acc = t ? acc1 : acc0;                                      \
                _Pragma("unroll")                                                       \
                for (int r = 0; r < 4; ++r) {                                           \
                    const float ex = EXP2F(fmaf(acc[r], K2, -K2));                      \
                    s_all[t][r] += ex;                                                  \
                    s_pos[t][r] += (lj == li[t][r]) ? ex : 0.0f;                        \
                }                                                                       \
            }                                                                           \
        } else {                                                                        \
            _Pragma("unroll")                                                           \
            for (int t = 0; t < 2; ++t) {                                               \
                const f32x4 acc = t ? acc1 : acc0;                                      \
                _Pragma("unroll")                                                       \
                for (int r = 0; r < 4; ++r) {                                           \
                    const int irow = i_base + t * 16 + quad * 4 + r;                    \
                    const float ex = EXP2F(fmaf(acc[r], K2, -K2));                      \
                    const bool valid = (jcol != irow);                                  \
                    const bool pos = valid && (lj == li[t][r]);                         \
                    s_all[t][r] += valid ? ex : 0.0f;                                   \
                    s_pos[t][r] += pos ? ex : 0.0f;                                     \
                }                                                                       \
            }                                                                           \
        }                                                                               \
        if (jt + 1 < NT) {                                                              \
            stw(LDSW, st_r, st_c, WR0);                                                 \
            stw(LDSW, st_r + 8, st_c, WR1);                                             \
        }                                                                               \
        __syncthreads();                                                                \
    }

    #pragma unroll 1
    for (int jt2 = 0; jt2 < NT; jt2 += 2) {
        STAGE(jt2,     lds0, lds1, pA0, pA1, pB0, pB1)   // even: read lds0, pf->pA, write pB
        STAGE(jt2 + 1, lds1, lds0, pB0, pB1, pA0, pA1)   // odd:  read lds1, pf->pB, write pA
    }
    #undef STAGE

    // Reduce over the 16 column-lanes within each quad, then one atomic per row.
    #pragma unroll
    for (int t = 0; t < 2; ++t) {
        #pragma unroll
        for (int r = 0; r < 4; ++r) {
            float a = s_all[t][r];
            float pp = s_pos[t][r];
            #pragma unroll
            for (int off = 1; off < 16; off <<= 1) {
                a += __shfl_xor(a, off);
                pp += __shfl_xor(pp, off);
            }
            if (col == 0) {
                const int irow = i_base + t * 16 + quad * 4 + r;
                atomicAdd(&Sall[irow], a);
                atomicAdd(&Spos[irow], pp);
            }
        }
    }

    // ---- Last block finalizes ----
    __threadfence();
    if (tid == 0) {
        const int old = __hip_atomic_fetch_add(done_ctr, 1, __ATOMIC_ACQ_REL,
                                               __HIP_MEMORY_SCOPE_AGENT);
        is_last = (old == (int)(gridDim.x - 1));
    }
    __syncthreads();
    if (!is_last) return;

    float sum = 0.0f;
    int cnt = 0;
    for (int i = tid; i < B_ROWS; i += 256) {
        const float sp = __hip_atomic_load(&Spos[i], __ATOMIC_RELAXED, __HIP_MEMORY_SCOPE_AGENT);
        const float sa = __hip_atomic_load(&Sall[i], __ATOMIC_RELAXED, __HIP_MEMORY_SCOPE_AGENT);
        if (sp > 0.0f) {
            sum += __logf(sa) - __logf(sp);  // fixed max M cancels
            ++cnt;
        }
    }
    #pragma unroll
    for (int off = 32; off; off >>= 1) {
        sum += __shfl_xor(sum, off);
        cnt += __shfl_xor(cnt, off);
    }
    if (lane == 0) { ssum[wave] = sum; scnt[wave] = cnt; }
    __syncthreads();
    if (tid == 0) {
        float s = 0.0f;
        int c = 0;
        #pragma unroll
        for (int w = 0; w < WPB; ++w) { s += ssum[w]; c += scnt[w]; }
        out[0] = (c > 0) ? s / (float)c : 0.0f;
    }
}

extern "C" void kernel_launch(void* const* d_in, const int* in_sizes, int n_in,
                              void* d_out, int out_size, void* d_ws, size_t ws_size,
                              hipStream_t stream) {
    const float* emb   = (const float*)d_in[0];
    const int* labels  = (const int*)d_in[1];
    float* out         = (float*)d_out;

    unsigned short* ebf = (unsigned short*)d_ws;                       // 4 MB bf16 normalized
    float* Sall = (float*)((char*)d_ws + (size_t)B_ROWS * DIM * 2);    // 32 KB
    float* Spos = Sall + B_ROWS;                                       // 32 KB
    int* done_ctr = (int*)(Spos + B_ROWS);

    normalize_k<<<B_ROWS / 4, 256, 0, stream>>>(emb, ebf, Sall, done_ctr);

    dim3 grid((B_ROWS / ROWS_PER_BLOCK) * (B_ROWS / JCHUNK));          // 64*32 = 2048
    sim_k<<<grid, 256, 0, stream>>>(ebf, labels, Sall, Spos, done_ctr, out);
}

// Round 5
// 110.871 us; speedup vs baseline: 3.7645x; 3.2523x over previous
//
#include <hip/hip_runtime.h>
#include <hip/hip_bf16.h>
#include <stdint.h>

#define B_ROWS 8192
#define DIM 256
#define JCHUNK 512
#define WPB 4   // waves per block
#define ROWS_PER_WAVE 64
#define ROWS_PER_BLOCK (WPB * ROWS_PER_WAVE)  // 256
#define NT (JCHUNK / 16)                      // 32 j-tiles per block
#define NTILES 4                              // A row-tiles per wave

typedef __bf16 bf16x8 __attribute__((ext_vector_type(8)));
typedef float f32x4 __attribute__((ext_vector_type(4)));

#if __has_builtin(__builtin_amdgcn_exp2f)
#define EXP2F(x) __builtin_amdgcn_exp2f(x)
#else
#define EXP2F(x) exp2f(x)
#endif

__device__ __forceinline__ unsigned short f2bf_rne(float f) {
    unsigned int u = __builtin_bit_cast(unsigned int, f);
    unsigned int r = (u + 0x7FFFu + ((u >> 16) & 1u)) >> 16;
    return (unsigned short)r;
}

// swizzled LDS tile: 16 rows x 512B; chunk c (16B) of row r at r*512 + ((c^r)&31)*16
__device__ __forceinline__ void stw(unsigned char* buf, int r, int c, uint4 v) {
    *reinterpret_cast<uint4*>(&buf[r * 512 + ((c ^ r) & 31) * 16]) = v;
}

// ---------------- Kernel 1: L2-normalize rows -> bf16, plus zero accumulators ----------------
__global__ __launch_bounds__(256) void normalize_k(const float* __restrict__ emb,
                                                   unsigned short* __restrict__ ebf,
                                                   float* __restrict__ Sall) {  // 2*8192 floats
    const int idx = blockIdx.x * 256 + threadIdx.x;
    if (idx < 4096) {
        float4 z = {0.f, 0.f, 0.f, 0.f};
        reinterpret_cast<float4*>(Sall)[idx] = z;
    }
    const int row = blockIdx.x * 4 + (threadIdx.x >> 6);
    const int lane = threadIdx.x & 63;  // 4 floats each covers DIM=256
    const float4 v = reinterpret_cast<const float4*>(emb + (size_t)row * DIM)[lane];
    float ss = v.x * v.x + v.y * v.y + v.z * v.z + v.w * v.w;
    #pragma unroll
    for (int off = 32; off; off >>= 1) ss += __shfl_xor(ss, off);
    const float scale = 1.0f / fmaxf(sqrtf(ss), 1e-12f);
    ushort4 o;
    o.x = f2bf_rne(v.x * scale);
    o.y = f2bf_rne(v.y * scale);
    o.z = f2bf_rne(v.z * scale);
    o.w = f2bf_rne(v.w * scale);
    reinterpret_cast<ushort4*>(ebf + (size_t)row * DIM)[lane] = o;
}

// ---------------- Kernel 2: fused sim + masked exp-sum ----------------
// 64 rows/wave (4 A-tiles, register/AGPR-resident, K=256). B-tile 16 cols x 512B
// staged in LDS (double-buffered, XOR swizzle), same-iteration register prefetch
// (R2-proven no-spill shape). No fences, no in-kernel finalize.
__global__ __launch_bounds__(256, 2) void sim_k(const unsigned short* __restrict__ ebf,
                                                const int* __restrict__ labels,
                                                float* __restrict__ Sall,
                                                float* __restrict__ Spos) {
    // exp((dot-1)/T) = exp2((dot-1) * INV_T*log2e)
    constexpr float K2 = 14.285714285714286f * 1.4426950408889634f;  // 20.60993
    __shared__ __align__(16) unsigned char lds0[8192];
    __shared__ __align__(16) unsigned char lds1[8192];
    __shared__ int lds_lab[JCHUNK];

    const int tid  = threadIdx.x;
    const int wave = tid >> 6;
    const int lane = tid & 63;
    const int col  = lane & 15;
    const int quad = lane >> 4;

    const int rowblk = blockIdx.x >> 4;            // 0..31
    const int jblk   = blockIdx.x & 15;            // 0..15
    const int i_base = rowblk * ROWS_PER_BLOCK + wave * ROWS_PER_WAVE;
    const int j0     = jblk * JCHUNK;

    // ---- Preload A-fragments (4 tiles x 8 K-steps) + row labels ----
    // lane L holds A[row = L&15][k = kk*32 + (L>>4)*8 + 0..7]
    bf16x8 afrag[NTILES][8];
    int li[NTILES][4];
    #pragma unroll
    for (int t = 0; t < NTILES; ++t) {
        const int arow = i_base + t * 16 + col;
        const uint4* ap = reinterpret_cast<const uint4*>(ebf) + (size_t)arow * 32 + quad;
        #pragma unroll
        for (int kk = 0; kk < 8; ++kk)
            afrag[t][kk] = __builtin_bit_cast(bf16x8, ap[kk * 4]);
        #pragma unroll
        for (int r = 0; r < 4; ++r)
            li[t][r] = labels[i_base + t * 16 + quad * 4 + r];
    }

    const int st_r = tid >> 5;      // 0..7
    const int st_c = tid & 31;
    const uint4* gB = reinterpret_cast<const uint4*>(ebf);

    // ---- Prologue: stage tile 0 into lds0; labels -> LDS ----
    lds_lab[tid] = labels[j0 + tid];
    lds_lab[256 + tid] = labels[j0 + 256 + tid];
    {
        const uint4 v0 = gB[(size_t)(j0 + st_r) * 32 + st_c];
        const uint4 v1 = gB[(size_t)(j0 + 8 + st_r) * 32 + st_c];
        stw(lds0, st_r, st_c, v0);
        stw(lds0, st_r + 8, st_c, v1);
    }
    __syncthreads();

    float s_all[NTILES][4] = {};
    float s_pos[NTILES][4] = {};

    for (int jt = 0; jt < NT; ++jt) {
        unsigned char* ldsR = (jt & 1) ? lds1 : lds0;
        unsigned char* ldsW = (jt & 1) ? lds0 : lds1;

        // issue next tile's global loads (consumed at the bottom of this iter)
        uint4 p0, p1;
        const bool havenext = (jt + 1) < NT;
        if (havenext) {
            const int jn = j0 + (jt + 1) * 16;
            p0 = gB[(size_t)(jn + st_r) * 32 + st_c];
            p1 = gB[(size_t)(jn + 8 + st_r) * 32 + st_c];
        }

        // MFMA: load each B-fragment then feed all 4 row-tiles (keeps bfrag liveness low)
        f32x4 acc[NTILES];
        #pragma unroll
        for (int t = 0; t < NTILES; ++t) acc[t] = (f32x4){0.f, 0.f, 0.f, 0.f};
        #pragma unroll
        for (int kk = 0; kk < 8; ++kk) {
            const int c = kk * 4 + quad;
            const bf16x8 bfrag = *reinterpret_cast<const bf16x8*>(
                &ldsR[col * 512 + ((c ^ col) & 31) * 16]);
            #pragma unroll
            for (int t = 0; t < NTILES; ++t)
                acc[t] = __builtin_amdgcn_mfma_f32_16x16x32_bf16(afrag[t][kk], bfrag, acc[t], 0, 0, 0);
        }

        const int jcol = j0 + jt * 16 + col;
        const int lj = lds_lab[jt * 16 + col];

        // Epilogue. D[row = quad*4+r][col]. Diagonal only possible when this 16-col
        // strip overlaps the wave's 64-row strip (wave-uniform branch).
        const int jt16 = j0 + jt * 16;
        const bool diag_possible = (jt16 < i_base + ROWS_PER_WAVE) && (i_base < jt16 + 16);
        if (!diag_possible) {
            #pragma unroll
            for (int t = 0; t < NTILES; ++t) {
                #pragma unroll
                for (int r = 0; r < 4; ++r) {
                    const float ex = EXP2F(fmaf(acc[t][r], K2, -K2));
                    s_all[t][r] += ex;
                    s_pos[t][r] += (lj == li[t][r]) ? ex : 0.0f;
                }
            }
        } else {
            #pragma unroll
            for (int t = 0; t < NTILES; ++t) {
                #pragma unroll
                for (int r = 0; r < 4; ++r) {
                    const int irow = i_base + t * 16 + quad * 4 + r;
                    const float ex = EXP2F(fmaf(acc[t][r], K2, -K2));
                    const bool valid = (jcol != irow);
                    const bool pos = valid && (lj == li[t][r]);
                    s_all[t][r] += valid ? ex : 0.0f;
                    s_pos[t][r] += pos ? ex : 0.0f;
                }
            }
        }

        // write next tile into the other buffer, then barrier
        if (havenext) {
            stw(ldsW, st_r, st_c, p0);
            stw(ldsW, st_r + 8, st_c, p1);
        }
        __syncthreads();
    }

    // Reduce over the 16 column-lanes within each quad, then one atomic per row.
    #pragma unroll
    for (int t = 0; t < NTILES; ++t) {
        #pragma unroll
        for (int r = 0; r < 4; ++r) {
            float a = s_all[t][r];
            float pp = s_pos[t][r];
            #pragma unroll
            for (int off = 1; off < 16; off <<= 1) {
                a += __shfl_xor(a, off);
                pp += __shfl_xor(pp, off);
            }
            if (col == 0) {
                const int irow = i_base + t * 16 + quad * 4 + r;
                atomicAdd(&Sall[irow], a);
                atomicAdd(&Spos[irow], pp);
            }
        }
    }
}

// ---------------- Kernel 3: per-row loss + mean ----------------
__global__ __launch_bounds__(1024) void finalize_k(const float* __restrict__ Sall,
                                                   const float* __restrict__ Spos,
                                                   float* __restrict__ out) {
    const int tid = threadIdx.x;
    float sum = 0.0f;
    int cnt = 0;
    #pragma unroll
    for (int k = 0; k < B_ROWS / 1024; ++k) {
        const int i = k * 1024 + tid;
        const float sp = Spos[i];
        const float sa = Sall[i];
        if (sp > 0.0f) {
            sum += __logf(__fdividef(sa, sp));  // log(sa)-log(sp); fixed max M cancels
            ++cnt;
        }
    }
    #pragma unroll
    for (int off = 32; off; off >>= 1) {
        sum += __shfl_xor(sum, off);
        cnt += __shfl_xor(cnt, off);
    }
    __shared__ float ssum[16];
    __shared__ int scnt[16];
    const int wave = tid >> 6, lane = tid & 63;
    if (lane == 0) { ssum[wave] = sum; scnt[wave] = cnt; }
    __syncthreads();
    if (tid == 0) {
        float s = 0.0f;
        int c = 0;
        #pragma unroll
        for (int w = 0; w < 16; ++w) { s += ssum[w]; c += scnt[w]; }
        out[0] = (c > 0) ? s / (float)c : 0.0f;
    }
}

extern "C" void kernel_launch(void* const* d_in, const int* in_sizes, int n_in,
                              void* d_out, int out_size, void* d_ws, size_t ws_size,
                              hipStream_t stream) {
    const float* emb   = (const float*)d_in[0];
    const int* labels  = (const int*)d_in[1];
    float* out         = (float*)d_out;

    unsigned short* ebf = (unsigned short*)d_ws;                       // 4 MB bf16 normalized
    float* Sall = (float*)((char*)d_ws + (size_t)B_ROWS * DIM * 2);    // 32 KB
    float* Spos = Sall + B_ROWS;                                       // 32 KB

    normalize_k<<<B_ROWS / 4, 256, 0, stream>>>(emb, ebf, Sall);

    dim3 grid((B_ROWS / ROWS_PER_BLOCK) * (B_ROWS / JCHUNK));          // 32*16 = 512
    sim_k<<<grid, 256, 0, stream>>>(ebf, labels, Sall, Spos);

    finalize_k<<<1, 1024, 0, stream>>>(Sall, Spos, out);
}